// Round 17
// baseline (121.748 us; speedup 1.0000x reference)
//
#include <hip/hip_runtime.h>
#include <math.h>
#include <stdint.h>

#define B_ 4
#define S_ 2048
#define DM_ 1024
#define DK_ 128

static constexpr float SCALE = 0.08838834764831845f; // 1/sqrt(128)

typedef __attribute__((ext_vector_type(8))) short short8;
typedef __attribute__((ext_vector_type(4))) float f32x4;
typedef __attribute__((ext_vector_type(4))) unsigned short us4;

__device__ __forceinline__ unsigned short bf16rne(float f){
  unsigned u = __float_as_uint(f);
  unsigned r = (u + 0x7FFFu + ((u>>16)&1u)) >> 16;
  return (unsigned short)r;
}
__device__ __forceinline__ float bf16tof(unsigned short h){
  return __uint_as_float((unsigned)h << 16);
}
// async global->LDS, 16B per lane; LDS dest = wave-uniform base + lane*16
__device__ __forceinline__ void gload16(const void* g, void* l){
  __builtin_amdgcn_global_load_lds(
      (const __attribute__((address_space(1))) void*)g,
      (__attribute__((address_space(3))) void*)l, 16, 0, 0);
}

// ---- X pre-convert: f32 [8192][1024] -> bf16 hi/lo MFMA-fragment image ----
__global__ __launch_bounds__(256) void xconv_kernel(
    const float* __restrict__ X,
    unsigned short* __restrict__ Xth, unsigned short* __restrict__ Xtl)
{
  const int kt = blockIdx.x & 31, mb = blockIdx.x >> 5;
  const int tid = threadIdx.x;
  const int unit = tid & 127, half = tid >> 7;
  const int g = unit >> 5, row = unit & 31;
  const float* src = X + (size_t)(mb*32 + row)*DM_ + kt*32 + g*8;
  float4 a = *reinterpret_cast<const float4*>(src);
  float4 b = *reinterpret_cast<const float4*>(src + 4);
  unsigned short* dst = (half ? Xtl : Xth) + ((size_t)(mb*32 + kt)*128 + unit)*8;
  if(half == 0){
    us4 h0 = {bf16rne(a.x),bf16rne(a.y),bf16rne(a.z),bf16rne(a.w)};
    us4 h1 = {bf16rne(b.x),bf16rne(b.y),bf16rne(b.z),bf16rne(b.w)};
    *(us4*)dst = h0; *(us4*)(dst+4) = h1;
  } else {
    us4 l0 = {bf16rne(a.x - bf16tof(bf16rne(a.x))), bf16rne(a.y - bf16tof(bf16rne(a.y))),
              bf16rne(a.z - bf16tof(bf16rne(a.z))), bf16rne(a.w - bf16tof(bf16rne(a.w)))};
    us4 l1 = {bf16rne(b.x - bf16tof(bf16rne(b.x))), bf16rne(b.y - bf16tof(bf16rne(b.y))),
              bf16rne(b.z - bf16tof(bf16rne(b.z))), bf16rne(b.w - bf16tof(bf16rne(b.w)))};
    *(us4*)dst = l0; *(us4*)(dst+4) = l1;
  }
}

// ---- W pre-convert: f32 [1024][128] -> bf16 hi/lo, pre-tiled [32 t][col][40] ----
__global__ __launch_bounds__(256) void wconv_kernel(
    const float* __restrict__ Wq, const float* __restrict__ Wk, const float* __restrict__ Wv,
    unsigned short* __restrict__ Wth, unsigned short* __restrict__ Wtl)
{
  const int t = blockIdx.x;       // k-tile 0..31
  const int which = blockIdx.y;   // 0..2
  const float* W = (which==0) ? Wq : ((which==1) ? Wk : Wv);
  const int tid = threadIdx.x;
  const size_t obase = ((size_t)which*32 + t)*5120;
  #pragma unroll
  for(int it=0; it<2; ++it){
    int idx = tid + 256*it;       // 0..511 -> (col, g)
    int col = idx & 127, g = idx >> 7;
    unsigned short hs[8], ls[8];
    #pragma unroll
    for(int j=0;j<8;j++){
      float f = W[(size_t)(t*32 + g*8 + j)*DK_ + col];
      unsigned short h = bf16rne(f);
      hs[j] = h;
      ls[j] = bf16rne(f - bf16tof(h));
    }
    size_t o = obase + (size_t)col*40 + g*8;
    *(us4*)&Wth[o]   = us4{hs[0],hs[1],hs[2],hs[3]};
    *(us4*)&Wth[o+4] = us4{hs[4],hs[5],hs[6],hs[7]};
    *(us4*)&Wtl[o]   = us4{ls[0],ls[1],ls[2],ls[3]};
    *(us4*)&Wtl[o+4] = us4{ls[4],ls[5],ls[6],ls[7]};
  }
}

// ---- QKV GEMM v9: bf16x3 MFMA for Q,K; bf16 hi-only for V (1 MFMA, half staging) ----
__global__ __launch_bounds__(256) void qkv_mfma_kernel(
    const unsigned short* __restrict__ Xth, const unsigned short* __restrict__ Xtl,
    const unsigned short* __restrict__ Wth, const unsigned short* __restrict__ Wtl,
    unsigned short* __restrict__ Qh, unsigned short* __restrict__ Ql,
    unsigned short* __restrict__ Kh, unsigned short* __restrict__ Kl,
    unsigned short* __restrict__ Vth)
{
  __shared__ __align__(16) unsigned char smem[49152];
  const int tid = threadIdx.x;
  const int w = tid >> 6, lane = tid & 63;
  const int l15 = lane & 15, g = lane >> 4;
  const int which = blockIdx.y;
  const bool vOnly = (which == 2);
  const int m0 = blockIdx.x * 32;
  const int mb = blockIdx.x;
  const unsigned char* Wh8 = (const unsigned char*)(Wth + (size_t)which*32*5120);
  const unsigned char* Wl8 = (const unsigned char*)(Wtl + (size_t)which*32*5120);
  const unsigned short* Asrc = ((w < 2) ? Xth : Xtl) + (size_t)(mb*32)*1024 + (w & 1)*512 + lane*8;
  const unsigned Adst = (unsigned)((w & 1)*1024) + ((w < 2) ? 0u : 2048u);
  const bool aSkip = (vOnly && w >= 2);          // V pass: no X-lo staging

  if(!aSkip) gload16(Asrc, smem + Adst);
  #pragma unroll
  for(int ii=0; ii<5; ++ii){
    int i = w + 4*ii;
    if(vOnly && i >= 10) continue;               // V pass: no W-lo staging
    const unsigned char* src = (i<10) ? (Wh8 + i*1024) : (Wl8 + (i-10)*1024);
    unsigned dst = 8192u + ((i<10) ? (unsigned)i*1024u : 10240u + (unsigned)(i-10)*1024u);
    gload16(src + lane*16, smem + dst);
  }

  f32x4 acc[4] = {f32x4{0,0,0,0},f32x4{0,0,0,0},f32x4{0,0,0,0},f32x4{0,0,0,0}};
  const int r = w >> 1, c0 = (w & 1)*4;
  const int aoff = (g*32 + r*16 + l15)*8;
  int buf = 0;
  for(int t=0; t<32; ++t){
    __syncthreads();
    if(t+1 < 32){
      if(!aSkip) gload16(Asrc + (size_t)(t+1)*1024, smem + (buf^1)*4096 + Adst);
      const unsigned char* WhT = Wh8 + (size_t)(t+1)*10240;
      const unsigned char* WlT = Wl8 + (size_t)(t+1)*10240;
      unsigned bbase = 8192u + (unsigned)(buf^1)*20480u;
      #pragma unroll
      for(int ii=0; ii<5; ++ii){
        int i = w + 4*ii;
        if(vOnly && i >= 10) continue;
        const unsigned char* src = (i<10) ? (WhT + i*1024) : (WlT + (i-10)*1024);
        unsigned dst = bbase + ((i<10) ? (unsigned)i*1024u : 10240u + (unsigned)(i-10)*1024u);
        gload16(src + lane*16, smem + dst);
      }
    }
    const unsigned short* Ab = (const unsigned short*)(smem + buf*4096);
    const unsigned short* Bhc = (const unsigned short*)(smem + 8192 + buf*20480);
    const unsigned short* Blc = Bhc + 5120;
    short8 ah = *(const short8*)&Ab[aoff];
    if(vOnly){
      #pragma unroll
      for(int c=0;c<4;c++){
        int boff = ((c0+c)*16 + l15)*40 + g*8;
        short8 bh = *(const short8*)&Bhc[boff];
        acc[c] = __builtin_amdgcn_mfma_f32_16x16x32_bf16(ah, bh, acc[c], 0, 0, 0);
      }
    } else {
      short8 al = *(const short8*)&Ab[1024 + aoff];
      #pragma unroll
      for(int c=0;c<4;c++){
        int boff = ((c0+c)*16 + l15)*40 + g*8;
        short8 bh = *(const short8*)&Bhc[boff];
        short8 bl = *(const short8*)&Blc[boff];
        acc[c] = __builtin_amdgcn_mfma_f32_16x16x32_bf16(ah, bh, acc[c], 0, 0, 0);
        acc[c] = __builtin_amdgcn_mfma_f32_16x16x32_bf16(ah, bl, acc[c], 0, 0, 0);
        acc[c] = __builtin_amdgcn_mfma_f32_16x16x32_bf16(al, bh, acc[c], 0, 0, 0);
      }
    }
    buf ^= 1;
  }
  const int b = m0 >> 11;
  const int orow0 = g*4;
  if(which != 2){
    unsigned short* Oh = (which==0) ? Qh : Kh;
    unsigned short* Ol = (which==0) ? Ql : Kl;
    #pragma unroll
    for(int c=0;c<4;c++){
      int col = (c0+c)*16 + l15;
      #pragma unroll
      for(int j=0;j<4;j++){
        float f = acc[c][j];
        unsigned short h = bf16rne(f);
        unsigned short lo = bf16rne(f - bf16tof(h));
        size_t o = (size_t)(m0 + r*16 + orow0 + j)*DK_ + col;
        Oh[o] = h; Ol[o] = lo;
      }
    }
  } else {
    __syncthreads();
    float* Tmp = (float*)smem;                 // [32][133]
    #pragma unroll
    for(int c=0;c<4;c++){
      int col = (c0+c)*16 + l15;
      #pragma unroll
      for(int j=0;j<4;j++)
        Tmp[(r*16 + orow0 + j)*133 + col] = acc[c][j];
    }
    __syncthreads();
    const int s0 = m0 & (S_-1);
    #pragma unroll
    for(int l2=0;l2<16;l2++){
      int p = tid + 256*l2;
      int d = p >> 5, rr = p & 31;
      Vth[(size_t)(b*DK_ + d)*S_ + s0 + rr] = bf16rne(Tmp[rr*133 + d]);
    }
  }
}

// ---- scores via bf16x3 MFMA: raw s (masked=0) -> attn; per-tile (max, exp-sum) partials ----
__global__ __launch_bounds__(256) void scores_kernel(
    const unsigned short* __restrict__ Qh, const unsigned short* __restrict__ Ql,
    const unsigned short* __restrict__ Kh, const unsigned short* __restrict__ Kl,
    float* __restrict__ attn, float* __restrict__ cmaxpart, float* __restrict__ csumpart)
{
  const int tj = blockIdx.x, ti = blockIdx.y, b = blockIdx.z;
  const int tid = threadIdx.x;
  const int q0 = ti*64, k0 = tj*64;
  if(tj > ti){                                 // upper triangle: zero-fill tile
    float4 z = {0.f,0.f,0.f,0.f};
    #pragma unroll
    for(int l=0;l<4;l++){
      int p = tid + 256*l;
      int r = p >> 4, c = (p & 15) << 2;
      *reinterpret_cast<float4*>(&attn[((size_t)(b*S_) + q0 + r)*S_ + k0 + c]) = z;
    }
    return;
  }
  __shared__ __align__(16) unsigned short sm[18432];   // 4 x [64][72]
  __shared__ float cred[16][64];
  __shared__ float csum[16][64];
  __shared__ float maxsh[64];
  unsigned short* Qhs = sm;
  unsigned short* Qls = sm + 4608;
  unsigned short* Khs = sm + 9216;
  unsigned short* Kls = sm + 13824;
  const int w = tid >> 6, lane = tid & 63, l15 = lane & 15, g = lane >> 4;
  f32x4 acc[4] = {f32x4{0,0,0,0},f32x4{0,0,0,0},f32x4{0,0,0,0},f32x4{0,0,0,0}};
  for(int kh=0; kh<2; ++kh){
    __syncthreads();
    #pragma unroll
    for(int l=0;l<2;l++){                      // stage 4 tiles (this K-half)
      int p = tid + 256*l;
      int row = p >> 3, cc = p & 7;
      size_t gq = (size_t)(b*S_ + q0 + row)*DK_ + kh*64 + cc*8;
      size_t gk = (size_t)(b*S_ + k0 + row)*DK_ + kh*64 + cc*8;
      int lo_ = row*72 + cc*8;
      *(short8*)&Qhs[lo_] = *(const short8*)&Qh[gq];
      *(short8*)&Qls[lo_] = *(const short8*)&Ql[gq];
      *(short8*)&Khs[lo_] = *(const short8*)&Kh[gk];
      *(short8*)&Kls[lo_] = *(const short8*)&Kl[gk];
    }
    __syncthreads();
    #pragma unroll
    for(int ks=0; ks<2; ++ks){                 // 2 x K=32 per half
      int ao = (w*16 + l15)*72 + ks*32 + g*8;
      short8 ah = *(const short8*)&Qhs[ao];
      short8 al = *(const short8*)&Qls[ao];
      #pragma unroll
      for(int c=0;c<4;c++){
        int bo = (c*16 + l15)*72 + ks*32 + g*8;
        short8 bh = *(const short8*)&Khs[bo];
        short8 bl = *(const short8*)&Kls[bo];
        acc[c] = __builtin_amdgcn_mfma_f32_16x16x32_bf16(ah, bh, acc[c], 0, 0, 0);
        acc[c] = __builtin_amdgcn_mfma_f32_16x16x32_bf16(ah, bl, acc[c], 0, 0, 0);
        acc[c] = __builtin_amdgcn_mfma_f32_16x16x32_bf16(al, bh, acc[c], 0, 0, 0);
      }
    }
  }
  const bool full = (ti > tj);
  const int qbase = q0 + w*16 + g*4;
  #pragma unroll
  for(int c=0;c<4;c++){
    int kcol = k0 + c*16 + l15;
    float cm = -INFINITY;
    #pragma unroll
    for(int j=0;j<4;j++){
      int q = qbase + j;
      float s = acc[c][j]*SCALE;
      bool valid = full || (q >= kcol);
      attn[((size_t)(b*S_) + q)*S_ + kcol] = valid ? s : 0.f;
      if(valid) cm = fmaxf(cm, s);
    }
    cred[w*4 + g][c*16 + l15] = cm;
  }
  __syncthreads();
  if(tid < 64){
    float m = cred[0][tid];
    #pragma unroll
    for(int gg=1;gg<16;gg++) m = fmaxf(m, cred[gg][tid]);
    maxsh[tid] = m;
    cmaxpart[((size_t)(b*S_) + k0 + tid)*32 + ti] = m;
  }
  __syncthreads();
  #pragma unroll
  for(int c=0;c<4;c++){
    int col = c*16 + l15;
    int kcol = k0 + col;
    float mcol = maxsh[col];
    float ps = 0.f;
    #pragma unroll
    for(int j=0;j<4;j++){
      int q = qbase + j;
      bool valid = full || (q >= kcol);
      if(valid) ps += __expf(acc[c][j]*SCALE - mcol);
    }
    csum[w*4 + g][col] = ps;
  }
  __syncthreads();
  if(tid < 64){
    float s = 0.f;
    #pragma unroll
    for(int gg=0;gg<16;gg++) s += csum[gg][tid];
    csumpart[((size_t)(b*S_) + k0 + tid)*32 + ti] = s;
  }
}

// ---- column flash-reduce in fixed tile order -> final max + reciprocal sums ----
__global__ __launch_bounds__(256) void colreduce_kernel(
    const float* __restrict__ cmaxpart, const float* __restrict__ csumpart,
    float* __restrict__ cmaxf, float* __restrict__ rcol)
{
  int i = blockIdx.x*256 + threadIdx.x;  // 0..8191 = b*S + k
  if(i >= B_*S_) return;
  int k = i & (S_-1);
  int t0 = k >> 6;
  float M = -INFINITY;
  for(int t=t0; t<32; t++) M = fmaxf(M, cmaxpart[(size_t)i*32 + t]);
  float s = 0.f;
  for(int t=t0; t<32; t++) s += csumpart[(size_t)i*32 + t] * __expf(cmaxpart[(size_t)i*32 + t] - M);
  cmaxf[i] = M;
  rcol[i] = 1.0f / s;
}

// ---- fused PV (P hi/lo x V hi): p=exp(s-M)*rcol written to attn in place; partials out ----
__global__ __launch_bounds__(256) void pv_kernel(
    float* __restrict__ attn, const float* __restrict__ cmaxf,
    const float* __restrict__ rcol,
    const unsigned short* __restrict__ Vth,
    float* __restrict__ part, int ns)
{
  __shared__ __align__(16) unsigned short sm[18432];  // Ah,Al [64][72]; Vh [128][72] = 36KB
  unsigned short* Ahs = sm;
  unsigned short* Als = sm + 4608;
  unsigned short* Vhs = sm + 9216;
  const int b = blockIdx.z, tid = threadIdx.x;
  const int sp = blockIdx.y;
  const int w = tid >> 6, lane = tid & 63, l15 = lane & 15, g = lane >> 4;
  const int t = 31 - (int)blockIdx.x;              // heavy tiles first
  const int q0 = t*64;
  const int nch = t + 1;
  const int lo = (sp*nch)/ns, hi = ((sp+1)*nch)/ns;
  f32x4 acc[8] = {f32x4{0,0,0,0},f32x4{0,0,0,0},f32x4{0,0,0,0},f32x4{0,0,0,0},
                  f32x4{0,0,0,0},f32x4{0,0,0,0},f32x4{0,0,0,0},f32x4{0,0,0,0}};
  const int er = tid >> 4, ekq = (tid & 15) << 2;
  for(int ch=lo; ch<hi; ++ch){
    const int k0c = ch*64;
    float4 m4 = *reinterpret_cast<const float4*>(&cmaxf[b*S_ + k0c + ekq]);
    float4 r4 = *reinterpret_cast<const float4*>(&rcol[b*S_ + k0c + ekq]);
    const bool diag = (ch == t);
    __syncthreads();
    #pragma unroll
    for(int rr=0; rr<4; ++rr){
      int row = rr*16 + er;
      size_t ea = ((size_t)(b*S_) + q0 + row)*S_ + k0c + ekq;
      float4 sv = *reinterpret_cast<const float4*>(&attn[ea]);
      float p0 = __expf(sv.x - m4.x)*r4.x;
      float p1 = __expf(sv.y - m4.y)*r4.y;
      float p2 = __expf(sv.z - m4.z)*r4.z;
      float p3 = __expf(sv.w - m4.w)*r4.w;
      if(diag){
        p0 = (row >= ekq+0) ? p0 : 0.f;
        p1 = (row >= ekq+1) ? p1 : 0.f;
        p2 = (row >= ekq+2) ? p2 : 0.f;
        p3 = (row >= ekq+3) ? p3 : 0.f;
      }
      float4 pv4 = {p0,p1,p2,p3};
      *reinterpret_cast<float4*>(&attn[ea]) = pv4; // normalized attention (final output)
      unsigned short h0=bf16rne(p0), h1=bf16rne(p1), h2=bf16rne(p2), h3=bf16rne(p3);
      *(us4*)&Ahs[row*72 + ekq] = us4{h0,h1,h2,h3};
      *(us4*)&Als[row*72 + ekq] = us4{ bf16rne(p0-bf16tof(h0)), bf16rne(p1-bf16tof(h1)),
                                       bf16rne(p2-bf16tof(h2)), bf16rne(p3-bf16tof(h3)) };
    }
    #pragma unroll
    for(int v=0; v<4; ++v){                        // V stage: [128 d][64 k] hi only
      int idx = v*256 + tid;
      int d = idx >> 3, c8 = (idx & 7) << 3;
      *(short8*)&Vhs[d*72 + c8] = *(const short8*)&Vth[(size_t)(b*DK_ + d)*S_ + k0c + c8];
    }
    __syncthreads();
    #pragma unroll
    for(int ks=0; ks<2; ++ks){
      int ao = (w*16 + l15)*72 + ks*32 + g*8;
      short8 ah = *(const short8*)&Ahs[ao];
      short8 al = *(const short8*)&Als[ao];
      #pragma unroll
      for(int c=0;c<8;c++){
        int bo = (c*16 + l15)*72 + ks*32 + g*8;
        short8 bh = *(const short8*)&Vhs[bo];
        acc[c] = __builtin_amdgcn_mfma_f32_16x16x32_bf16(ah, bh, acc[c], 0, 0, 0);
        acc[c] = __builtin_amdgcn_mfma_f32_16x16x32_bf16(al, bh, acc[c], 0, 0, 0);
      }
    }
  }
  float* pout = part + (((size_t)(sp*B_ + b))*S_ + q0)*DK_;
  #pragma unroll
  for(int c=0;c<8;c++){
    #pragma unroll
    for(int j=0;j<4;j++){
      int qrow = w*16 + g*4 + j;
      pout[(size_t)qrow*DK_ + c*16 + l15] = acc[c][j];
    }
  }
}

// ---- sum split-K partials in fixed order ----
__global__ __launch_bounds__(256) void pvreduce_kernel(
    const float* __restrict__ part, float* __restrict__ out, int ns)
{
  const int N4 = (B_*S_*DK_)/4;   // 262144 float4
  int i = blockIdx.x*256 + threadIdx.x;
  if(i >= N4) return;
  const float4* p = reinterpret_cast<const float4*>(part);
  float4 a = p[i];
  for(int s=1; s<ns; ++s){
    float4 q = p[(size_t)s*N4 + i];
    a.x += q.x; a.y += q.y; a.z += q.z; a.w += q.w;
  }
  reinterpret_cast<float4*>(out)[i] = a;
}

extern "C" void kernel_launch(void* const* d_in, const int* in_sizes, int n_in,
                              void* d_out, int out_size, void* d_ws, size_t ws_size,
                              hipStream_t stream)
{
  (void)in_sizes; (void)n_in; (void)out_size;
  const float* X  = (const float*)d_in[0];
  const float* Wq = (const float*)d_in[1];
  const float* Wk = (const float*)d_in[2];
  const float* Wv = (const float*)d_in[3];
  float* out  = (float*)d_out;
  float* attn = out + (size_t)B_*S_*DK_;            // attention output region (64MB)

  // X bf16 hi/lo images live INSIDE the attn region (dead once scores runs)
  unsigned short* Xth = (unsigned short*)attn;            // 16MB
  unsigned short* Xtl = Xth + (size_t)8388608;            // 16MB

  float* ws = (float*)d_ws;
  float* cmaxf    = ws;                              // [8192]
  float* rcol     = ws + 8192;                       // [8192]
  float* csumpart = ws + 16384;                      // [8192*32]
  float* cmaxpart = ws + 278528;                     // [8192*32]
  unsigned short* Wth = (unsigned short*)(ws + 540672);   // [3][32][5120] shorts
  unsigned short* Wtl = (unsigned short*)(ws + 786432);
  unsigned short* Qh  = (unsigned short*)(ws + 1032192);  // [8192][128] shorts each
  unsigned short* Ql  = (unsigned short*)(ws + 1556480);
  unsigned short* Kh  = (unsigned short*)(ws + 2080768);
  unsigned short* Kl  = (unsigned short*)(ws + 2605056);
  unsigned short* Vth = (unsigned short*)(ws + 3129344);  // [4][128][2048] shorts
  const size_t base = 3653632;                       // floats used so far
  float* part    = ws + base;                        // [ns][4][2048][128]

  int ns = 4;
  if(ws_size < (base + (size_t)4*1048576)*sizeof(float)) ns = 2;
  if(ws_size < (base + (size_t)2*1048576)*sizeof(float)) ns = 1;

  xconv_kernel<<<dim3(8192), dim3(256), 0, stream>>>(X, Xth, Xtl);
  wconv_kernel<<<dim3(32,3), dim3(256), 0, stream>>>(Wq, Wk, Wv, Wth, Wtl);
  qkv_mfma_kernel<<<dim3(256,3), dim3(256), 0, stream>>>(Xth, Xtl, Wth, Wtl, Qh, Ql, Kh, Kl, Vth);
  scores_kernel<<<dim3(32,32,4), dim3(256), 0, stream>>>(Qh, Ql, Kh, Kl, attn, cmaxpart, csumpart);
  colreduce_kernel<<<dim3(32), dim3(256), 0, stream>>>(cmaxpart, csumpart, cmaxf, rcol);
  pv_kernel<<<dim3(32,ns,4), dim3(256), 0, stream>>>(attn, cmaxf, rcol, Vth, part, ns);
  pvreduce_kernel<<<dim3(1024), dim3(256), 0, stream>>>(part, out, ns);
}

// Round 18
// 113.986 us; speedup vs baseline: 1.0681x; 1.0681x over previous
//
#include <hip/hip_runtime.h>
#include <math.h>
#include <stdint.h>

#define B_ 4
#define S_ 2048
#define DM_ 1024
#define DK_ 128

static constexpr float SCALE = 0.08838834764831845f; // 1/sqrt(128)

typedef __attribute__((ext_vector_type(8))) short short8;
typedef __attribute__((ext_vector_type(4))) float f32x4;
typedef __attribute__((ext_vector_type(4))) unsigned short us4;

__device__ __forceinline__ unsigned short bf16rne(float f){
  unsigned u = __float_as_uint(f);
  unsigned r = (u + 0x7FFFu + ((u>>16)&1u)) >> 16;
  return (unsigned short)r;
}
__device__ __forceinline__ float bf16tof(unsigned short h){
  return __uint_as_float((unsigned)h << 16);
}
// async global->LDS, 16B per lane; LDS dest = wave-uniform base + lane*16
__device__ __forceinline__ void gload16(const void* g, void* l){
  __builtin_amdgcn_global_load_lds(
      (const __attribute__((address_space(1))) void*)g,
      (__attribute__((address_space(3))) void*)l, 16, 0, 0);
}

// ---- X pre-convert: f32 [8192][1024] -> bf16 hi/lo MFMA-fragment image ----
__global__ __launch_bounds__(256) void xconv_kernel(
    const float* __restrict__ X,
    unsigned short* __restrict__ Xth, unsigned short* __restrict__ Xtl)
{
  const int kt = blockIdx.x & 31, mb = blockIdx.x >> 5;
  const int tid = threadIdx.x;
  const int unit = tid & 127, half = tid >> 7;
  const int g = unit >> 5, row = unit & 31;
  const float* src = X + (size_t)(mb*32 + row)*DM_ + kt*32 + g*8;
  float4 a = *reinterpret_cast<const float4*>(src);
  float4 b = *reinterpret_cast<const float4*>(src + 4);
  unsigned short* dst = (half ? Xtl : Xth) + ((size_t)(mb*32 + kt)*128 + unit)*8;
  if(half == 0){
    us4 h0 = {bf16rne(a.x),bf16rne(a.y),bf16rne(a.z),bf16rne(a.w)};
    us4 h1 = {bf16rne(b.x),bf16rne(b.y),bf16rne(b.z),bf16rne(b.w)};
    *(us4*)dst = h0; *(us4*)(dst+4) = h1;
  } else {
    us4 l0 = {bf16rne(a.x - bf16tof(bf16rne(a.x))), bf16rne(a.y - bf16tof(bf16rne(a.y))),
              bf16rne(a.z - bf16tof(bf16rne(a.z))), bf16rne(a.w - bf16tof(bf16rne(a.w)))};
    us4 l1 = {bf16rne(b.x - bf16tof(bf16rne(b.x))), bf16rne(b.y - bf16tof(bf16rne(b.y))),
              bf16rne(b.z - bf16tof(bf16rne(b.z))), bf16rne(b.w - bf16tof(bf16rne(b.w)))};
    *(us4*)dst = l0; *(us4*)(dst+4) = l1;
  }
}

// ---- W pre-convert: f32 [1024][128] -> bf16 hi/lo, pre-tiled [32 t][col][40] ----
__global__ __launch_bounds__(256) void wconv_kernel(
    const float* __restrict__ Wq, const float* __restrict__ Wk, const float* __restrict__ Wv,
    unsigned short* __restrict__ Wth, unsigned short* __restrict__ Wtl)
{
  const int t = blockIdx.x;       // k-tile 0..31
  const int which = blockIdx.y;   // 0..2
  const float* W = (which==0) ? Wq : ((which==1) ? Wk : Wv);
  const int tid = threadIdx.x;
  const size_t obase = ((size_t)which*32 + t)*5120;
  #pragma unroll
  for(int it=0; it<2; ++it){
    int idx = tid + 256*it;       // 0..511 -> (col, g)
    int col = idx & 127, g = idx >> 7;
    unsigned short hs[8], ls[8];
    #pragma unroll
    for(int j=0;j<8;j++){
      float f = W[(size_t)(t*32 + g*8 + j)*DK_ + col];
      unsigned short h = bf16rne(f);
      hs[j] = h;
      ls[j] = bf16rne(f - bf16tof(h));
    }
    size_t o = obase + (size_t)col*40 + g*8;
    *(us4*)&Wth[o]   = us4{hs[0],hs[1],hs[2],hs[3]};
    *(us4*)&Wth[o+4] = us4{hs[4],hs[5],hs[6],hs[7]};
    *(us4*)&Wtl[o]   = us4{ls[0],ls[1],ls[2],ls[3]};
    *(us4*)&Wtl[o+4] = us4{ls[4],ls[5],ls[6],ls[7]};
  }
}

// ---- QKV GEMM v9: bf16x3 MFMA for Q,K; bf16 hi-only for V (1 MFMA, half staging) ----
__global__ __launch_bounds__(256) void qkv_mfma_kernel(
    const unsigned short* __restrict__ Xth, const unsigned short* __restrict__ Xtl,
    const unsigned short* __restrict__ Wth, const unsigned short* __restrict__ Wtl,
    unsigned short* __restrict__ Qh, unsigned short* __restrict__ Ql,
    unsigned short* __restrict__ Kh, unsigned short* __restrict__ Kl,
    unsigned short* __restrict__ Vth)
{
  __shared__ __align__(16) unsigned char smem[49152];
  const int tid = threadIdx.x;
  const int w = tid >> 6, lane = tid & 63;
  const int l15 = lane & 15, g = lane >> 4;
  const int which = blockIdx.y;
  const bool vOnly = (which == 2);
  const int m0 = blockIdx.x * 32;
  const int mb = blockIdx.x;
  const unsigned char* Wh8 = (const unsigned char*)(Wth + (size_t)which*32*5120);
  const unsigned char* Wl8 = (const unsigned char*)(Wtl + (size_t)which*32*5120);
  const unsigned short* Asrc = ((w < 2) ? Xth : Xtl) + (size_t)(mb*32)*1024 + (w & 1)*512 + lane*8;
  const unsigned Adst = (unsigned)((w & 1)*1024) + ((w < 2) ? 0u : 2048u);
  const bool aSkip = (vOnly && w >= 2);          // V pass: no X-lo staging

  if(!aSkip) gload16(Asrc, smem + Adst);
  #pragma unroll
  for(int ii=0; ii<5; ++ii){
    int i = w + 4*ii;
    if(vOnly && i >= 10) continue;               // V pass: no W-lo staging
    const unsigned char* src = (i<10) ? (Wh8 + i*1024) : (Wl8 + (i-10)*1024);
    unsigned dst = 8192u + ((i<10) ? (unsigned)i*1024u : 10240u + (unsigned)(i-10)*1024u);
    gload16(src + lane*16, smem + dst);
  }

  f32x4 acc[4] = {f32x4{0,0,0,0},f32x4{0,0,0,0},f32x4{0,0,0,0},f32x4{0,0,0,0}};
  const int r = w >> 1, c0 = (w & 1)*4;
  const int aoff = (g*32 + r*16 + l15)*8;
  int buf = 0;
  for(int t=0; t<32; ++t){
    __syncthreads();
    if(t+1 < 32){
      if(!aSkip) gload16(Asrc + (size_t)(t+1)*1024, smem + (buf^1)*4096 + Adst);
      const unsigned char* WhT = Wh8 + (size_t)(t+1)*10240;
      const unsigned char* WlT = Wl8 + (size_t)(t+1)*10240;
      unsigned bbase = 8192u + (unsigned)(buf^1)*20480u;
      #pragma unroll
      for(int ii=0; ii<5; ++ii){
        int i = w + 4*ii;
        if(vOnly && i >= 10) continue;
        const unsigned char* src = (i<10) ? (WhT + i*1024) : (WlT + (i-10)*1024);
        unsigned dst = bbase + ((i<10) ? (unsigned)i*1024u : 10240u + (unsigned)(i-10)*1024u);
        gload16(src + lane*16, smem + dst);
      }
    }
    const unsigned short* Ab = (const unsigned short*)(smem + buf*4096);
    const unsigned short* Bhc = (const unsigned short*)(smem + 8192 + buf*20480);
    const unsigned short* Blc = Bhc + 5120;
    short8 ah = *(const short8*)&Ab[aoff];
    if(vOnly){
      #pragma unroll
      for(int c=0;c<4;c++){
        int boff = ((c0+c)*16 + l15)*40 + g*8;
        short8 bh = *(const short8*)&Bhc[boff];
        acc[c] = __builtin_amdgcn_mfma_f32_16x16x32_bf16(ah, bh, acc[c], 0, 0, 0);
      }
    } else {
      short8 al = *(const short8*)&Ab[1024 + aoff];
      #pragma unroll
      for(int c=0;c<4;c++){
        int boff = ((c0+c)*16 + l15)*40 + g*8;
        short8 bh = *(const short8*)&Bhc[boff];
        short8 bl = *(const short8*)&Blc[boff];
        acc[c] = __builtin_amdgcn_mfma_f32_16x16x32_bf16(ah, bh, acc[c], 0, 0, 0);
        acc[c] = __builtin_amdgcn_mfma_f32_16x16x32_bf16(ah, bl, acc[c], 0, 0, 0);
        acc[c] = __builtin_amdgcn_mfma_f32_16x16x32_bf16(al, bh, acc[c], 0, 0, 0);
      }
    }
    buf ^= 1;
  }
  const int b = m0 >> 11;
  const int orow0 = g*4;
  if(which != 2){
    unsigned short* Oh = (which==0) ? Qh : Kh;
    unsigned short* Ol = (which==0) ? Ql : Kl;
    #pragma unroll
    for(int c=0;c<4;c++){
      int col = (c0+c)*16 + l15;
      #pragma unroll
      for(int j=0;j<4;j++){
        float f = acc[c][j];
        unsigned short h = bf16rne(f);
        unsigned short lo = bf16rne(f - bf16tof(h));
        size_t o = (size_t)(m0 + r*16 + orow0 + j)*DK_ + col;
        Oh[o] = h; Ol[o] = lo;
      }
    }
  } else {
    __syncthreads();
    float* Tmp = (float*)smem;                 // [32][133]
    #pragma unroll
    for(int c=0;c<4;c++){
      int col = (c0+c)*16 + l15;
      #pragma unroll
      for(int j=0;j<4;j++)
        Tmp[(r*16 + orow0 + j)*133 + col] = acc[c][j];
    }
    __syncthreads();
    const int s0 = m0 & (S_-1);
    #pragma unroll
    for(int l2=0;l2<16;l2++){
      int p = tid + 256*l2;
      int d = p >> 5, rr = p & 31;
      Vth[(size_t)(b*DK_ + d)*S_ + s0 + rr] = bf16rne(Tmp[rr*133 + d]);
    }
  }
}

// ---- scores via bf16x3 MFMA: raw s (masked=0) -> attn; per-tile (max, exp-sum) partials ----
__global__ __launch_bounds__(256) void scores_kernel(
    const unsigned short* __restrict__ Qh, const unsigned short* __restrict__ Ql,
    const unsigned short* __restrict__ Kh, const unsigned short* __restrict__ Kl,
    float* __restrict__ attn, float* __restrict__ cmaxpart, float* __restrict__ csumpart)
{
  const int tj = blockIdx.x, ti = blockIdx.y, b = blockIdx.z;
  const int tid = threadIdx.x;
  const int q0 = ti*64, k0 = tj*64;
  if(tj > ti){                                 // upper triangle: zero-fill tile
    float4 z = {0.f,0.f,0.f,0.f};
    #pragma unroll
    for(int l=0;l<4;l++){
      int p = tid + 256*l;
      int r = p >> 4, c = (p & 15) << 2;
      *reinterpret_cast<float4*>(&attn[((size_t)(b*S_) + q0 + r)*S_ + k0 + c]) = z;
    }
    return;
  }
  __shared__ __align__(16) unsigned short sm[18432];   // 4 x [64][72]
  __shared__ float cred[16][64];
  __shared__ float csum[16][64];
  __shared__ float maxsh[64];
  unsigned short* Qhs = sm;
  unsigned short* Qls = sm + 4608;
  unsigned short* Khs = sm + 9216;
  unsigned short* Kls = sm + 13824;
  const int w = tid >> 6, lane = tid & 63, l15 = lane & 15, g = lane >> 4;
  f32x4 acc[4] = {f32x4{0,0,0,0},f32x4{0,0,0,0},f32x4{0,0,0,0},f32x4{0,0,0,0}};
  for(int kh=0; kh<2; ++kh){
    __syncthreads();
    #pragma unroll
    for(int l=0;l<2;l++){                      // stage 4 tiles (this K-half)
      int p = tid + 256*l;
      int row = p >> 3, cc = p & 7;
      size_t gq = (size_t)(b*S_ + q0 + row)*DK_ + kh*64 + cc*8;
      size_t gk = (size_t)(b*S_ + k0 + row)*DK_ + kh*64 + cc*8;
      int lo_ = row*72 + cc*8;
      *(short8*)&Qhs[lo_] = *(const short8*)&Qh[gq];
      *(short8*)&Qls[lo_] = *(const short8*)&Ql[gq];
      *(short8*)&Khs[lo_] = *(const short8*)&Kh[gk];
      *(short8*)&Kls[lo_] = *(const short8*)&Kl[gk];
    }
    __syncthreads();
    #pragma unroll
    for(int ks=0; ks<2; ++ks){                 // 2 x K=32 per half
      int ao = (w*16 + l15)*72 + ks*32 + g*8;
      short8 ah = *(const short8*)&Qhs[ao];
      short8 al = *(const short8*)&Qls[ao];
      #pragma unroll
      for(int c=0;c<4;c++){
        int bo = (c*16 + l15)*72 + ks*32 + g*8;
        short8 bh = *(const short8*)&Khs[bo];
        short8 bl = *(const short8*)&Kls[bo];
        acc[c] = __builtin_amdgcn_mfma_f32_16x16x32_bf16(ah, bh, acc[c], 0, 0, 0);
        acc[c] = __builtin_amdgcn_mfma_f32_16x16x32_bf16(ah, bl, acc[c], 0, 0, 0);
        acc[c] = __builtin_amdgcn_mfma_f32_16x16x32_bf16(al, bh, acc[c], 0, 0, 0);
      }
    }
  }
  const bool full = (ti > tj);
  const int qbase = q0 + w*16 + g*4;
  #pragma unroll
  for(int c=0;c<4;c++){
    int kcol = k0 + c*16 + l15;
    float cm = -INFINITY;
    #pragma unroll
    for(int j=0;j<4;j++){
      int q = qbase + j;
      float s = acc[c][j]*SCALE;
      bool valid = full || (q >= kcol);
      attn[((size_t)(b*S_) + q)*S_ + kcol] = valid ? s : 0.f;
      if(valid) cm = fmaxf(cm, s);
    }
    cred[w*4 + g][c*16 + l15] = cm;
  }
  __syncthreads();
  if(tid < 64){
    float m = cred[0][tid];
    #pragma unroll
    for(int gg=1;gg<16;gg++) m = fmaxf(m, cred[gg][tid]);
    maxsh[tid] = m;
    cmaxpart[((size_t)(b*S_) + k0 + tid)*32 + ti] = m;
  }
  __syncthreads();
  #pragma unroll
  for(int c=0;c<4;c++){
    int col = c*16 + l15;
    int kcol = k0 + col;
    float mcol = maxsh[col];
    float ps = 0.f;
    #pragma unroll
    for(int j=0;j<4;j++){
      int q = qbase + j;
      bool valid = full || (q >= kcol);
      if(valid) ps += __expf(acc[c][j]*SCALE - mcol);
    }
    csum[w*4 + g][col] = ps;
  }
  __syncthreads();
  if(tid < 64){
    float s = 0.f;
    #pragma unroll
    for(int gg=0;gg<16;gg++) s += csum[gg][tid];
    csumpart[((size_t)(b*S_) + k0 + tid)*32 + ti] = s;
  }
}

// ---- column flash-reduce in fixed tile order -> final max + reciprocal sums ----
__global__ __launch_bounds__(256) void colreduce_kernel(
    const float* __restrict__ cmaxpart, const float* __restrict__ csumpart,
    float* __restrict__ cmaxf, float* __restrict__ rcol)
{
  int i = blockIdx.x*256 + threadIdx.x;  // 0..8191 = b*S + k
  if(i >= B_*S_) return;
  int k = i & (S_-1);
  int t0 = k >> 6;
  float M = -INFINITY;
  for(int t=t0; t<32; t++) M = fmaxf(M, cmaxpart[(size_t)i*32 + t]);
  float s = 0.f;
  for(int t=t0; t<32; t++) s += csumpart[(size_t)i*32 + t] * __expf(cmaxpart[(size_t)i*32 + t] - M);
  cmaxf[i] = M;
  rcol[i] = 1.0f / s;
}

// ---- fused PV: V staged via gload16 (pre-swizzled source, linear LDS); P hi/lo x V hi ----
__global__ __launch_bounds__(256) void pv_kernel(
    float* __restrict__ attn, const float* __restrict__ cmaxf,
    const float* __restrict__ rcol,
    const unsigned short* __restrict__ Vth,
    float* __restrict__ part, int ns)
{
  // shorts: Ahs [64][72] @0, Als @4608, VhsL linear [128][64] @9216  -> 34816 B
  __shared__ __align__(16) unsigned short sm[17408];
  unsigned short* Ahs = sm;
  unsigned short* Als = sm + 4608;
  unsigned short* VhsL = sm + 9216;
  const int b = blockIdx.z, tid = threadIdx.x;
  const int sp = blockIdx.y;
  const int w = tid >> 6, lane = tid & 63, l15 = lane & 15, g = lane >> 4;
  const int t = 31 - (int)blockIdx.x;              // heavy tiles first
  const int q0 = t*64;
  const int nch = t + 1;
  const int lo = (sp*nch)/ns, hi = ((sp+1)*nch)/ns;
  f32x4 acc[8] = {f32x4{0,0,0,0},f32x4{0,0,0,0},f32x4{0,0,0,0},f32x4{0,0,0,0},
                  f32x4{0,0,0,0},f32x4{0,0,0,0},f32x4{0,0,0,0},f32x4{0,0,0,0}};
  const int er = tid >> 4, ekq = (tid & 15) << 2;
  const unsigned short* Vb = Vth + (size_t)(b*DK_)*S_;
  for(int ch=lo; ch<hi; ++ch){
    const int k0c = ch*64;
    float4 m4 = *reinterpret_cast<const float4*>(&cmaxf[b*S_ + k0c + ekq]);
    float4 r4 = *reinterpret_cast<const float4*>(&rcol[b*S_ + k0c + ekq]);
    const bool diag = (ch == t);
    __syncthreads();                               // prev MFMA readers done
    // issue V stage FIRST (async; flies under the exp phase; drained at next barrier)
    #pragma unroll
    for(int v=0; v<4; ++v){
      int idx = v*256 + tid;                       // 16B unit 0..1023
      int row = idx >> 3, sl = idx & 7;
      int ssl = sl ^ (row & 7);                    // pre-swizzled source slot
      gload16(Vb + (size_t)row*S_ + k0c + ssl*8, (unsigned char*)VhsL + idx*16);
    }
    #pragma unroll
    for(int rr=0; rr<4; ++rr){
      int row = rr*16 + er;
      size_t ea = ((size_t)(b*S_) + q0 + row)*S_ + k0c + ekq;
      float4 sv = *reinterpret_cast<const float4*>(&attn[ea]);
      float p0 = __expf(sv.x - m4.x)*r4.x;
      float p1 = __expf(sv.y - m4.y)*r4.y;
      float p2 = __expf(sv.z - m4.z)*r4.z;
      float p3 = __expf(sv.w - m4.w)*r4.w;
      if(diag){
        p0 = (row >= ekq+0) ? p0 : 0.f;
        p1 = (row >= ekq+1) ? p1 : 0.f;
        p2 = (row >= ekq+2) ? p2 : 0.f;
        p3 = (row >= ekq+3) ? p3 : 0.f;
      }
      float4 pv4 = {p0,p1,p2,p3};
      *reinterpret_cast<float4*>(&attn[ea]) = pv4; // normalized attention (final output)
      unsigned short h0=bf16rne(p0), h1=bf16rne(p1), h2=bf16rne(p2), h3=bf16rne(p3);
      *(us4*)&Ahs[row*72 + ekq] = us4{h0,h1,h2,h3};
      *(us4*)&Als[row*72 + ekq] = us4{ bf16rne(p0-bf16tof(h0)), bf16rne(p1-bf16tof(h1)),
                                       bf16rne(p2-bf16tof(h2)), bf16rne(p3-bf16tof(h3)) };
    }
    __syncthreads();                               // drains gloads + ds_writes
    #pragma unroll
    for(int ks=0; ks<2; ++ks){
      int ao = (w*16 + l15)*72 + ks*32 + g*8;
      short8 ah = *(const short8*)&Ahs[ao];
      short8 al = *(const short8*)&Als[ao];
      #pragma unroll
      for(int c=0;c<8;c++){
        int row = c*16 + l15;
        int bo = row*64 + (((ks*4 + g) ^ (l15 & 7)) << 3);   // un-swizzle on read
        short8 bh = *(const short8*)&VhsL[bo];
        acc[c] = __builtin_amdgcn_mfma_f32_16x16x32_bf16(ah, bh, acc[c], 0, 0, 0);
        acc[c] = __builtin_amdgcn_mfma_f32_16x16x32_bf16(al, bh, acc[c], 0, 0, 0);
      }
    }
  }
  float* pout = part + (((size_t)(sp*B_ + b))*S_ + q0)*DK_;
  #pragma unroll
  for(int c=0;c<8;c++){
    #pragma unroll
    for(int j=0;j<4;j++){
      int qrow = w*16 + g*4 + j;
      pout[(size_t)qrow*DK_ + c*16 + l15] = acc[c][j];
    }
  }
}

// ---- sum split-K partials in fixed order ----
__global__ __launch_bounds__(256) void pvreduce_kernel(
    const float* __restrict__ part, float* __restrict__ out, int ns)
{
  const int N4 = (B_*S_*DK_)/4;   // 262144 float4
  int i = blockIdx.x*256 + threadIdx.x;
  if(i >= N4) return;
  const float4* p = reinterpret_cast<const float4*>(part);
  float4 a = p[i];
  for(int s=1; s<ns; ++s){
    float4 q = p[(size_t)s*N4 + i];
    a.x += q.x; a.y += q.y; a.z += q.z; a.w += q.w;
  }
  reinterpret_cast<float4*>(out)[i] = a;
}

extern "C" void kernel_launch(void* const* d_in, const int* in_sizes, int n_in,
                              void* d_out, int out_size, void* d_ws, size_t ws_size,
                              hipStream_t stream)
{
  (void)in_sizes; (void)n_in; (void)out_size;
  const float* X  = (const float*)d_in[0];
  const float* Wq = (const float*)d_in[1];
  const float* Wk = (const float*)d_in[2];
  const float* Wv = (const float*)d_in[3];
  float* out  = (float*)d_out;
  float* attn = out + (size_t)B_*S_*DK_;            // attention output region (64MB)

  // X bf16 hi/lo images live INSIDE the attn region (dead once scores runs)
  unsigned short* Xth = (unsigned short*)attn;            // 16MB
  unsigned short* Xtl = Xth + (size_t)8388608;            // 16MB

  float* ws = (float*)d_ws;
  float* cmaxf    = ws;                              // [8192]
  float* rcol     = ws + 8192;                       // [8192]
  float* csumpart = ws + 16384;                      // [8192*32]
  float* cmaxpart = ws + 278528;                     // [8192*32]
  unsigned short* Wth = (unsigned short*)(ws + 540672);   // [3][32][5120] shorts
  unsigned short* Wtl = (unsigned short*)(ws + 786432);
  unsigned short* Qh  = (unsigned short*)(ws + 1032192);  // [8192][128] shorts each
  unsigned short* Ql  = (unsigned short*)(ws + 1556480);
  unsigned short* Kh  = (unsigned short*)(ws + 2080768);
  unsigned short* Kl  = (unsigned short*)(ws + 2605056);
  unsigned short* Vth = (unsigned short*)(ws + 3129344);  // [4][128][2048] shorts
  const size_t base = 3653632;                       // floats used so far
  float* part    = ws + base;                        // [ns][4][2048][128]

  int ns = 8;
  if(ws_size < (base + (size_t)8*1048576)*sizeof(float)) ns = 4;
  if(ws_size < (base + (size_t)4*1048576)*sizeof(float)) ns = 2;
  if(ws_size < (base + (size_t)2*1048576)*sizeof(float)) ns = 1;

  xconv_kernel<<<dim3(8192), dim3(256), 0, stream>>>(X, Xth, Xtl);
  wconv_kernel<<<dim3(32,3), dim3(256), 0, stream>>>(Wq, Wk, Wv, Wth, Wtl);
  qkv_mfma_kernel<<<dim3(256,3), dim3(256), 0, stream>>>(Xth, Xtl, Wth, Wtl, Qh, Ql, Kh, Kl, Vth);
  scores_kernel<<<dim3(32,32,4), dim3(256), 0, stream>>>(Qh, Ql, Kh, Kl, attn, cmaxpart, csumpart);
  colreduce_kernel<<<dim3(32), dim3(256), 0, stream>>>(cmaxpart, csumpart, cmaxf, rcol);
  pv_kernel<<<dim3(32,ns,4), dim3(256), 0, stream>>>(attn, cmaxf, rcol, Vth, part, ns);
  pvreduce_kernel<<<dim3(1024), dim3(256), 0, stream>>>(part, out, ns);
}

// Round 19
// 111.948 us; speedup vs baseline: 1.0875x; 1.0182x over previous
//
#include <hip/hip_runtime.h>
#include <math.h>
#include <stdint.h>

#define B_ 4
#define S_ 2048
#define DM_ 1024
#define DK_ 128

static constexpr float SCALE = 0.08838834764831845f; // 1/sqrt(128)

typedef __attribute__((ext_vector_type(8))) short short8;
typedef __attribute__((ext_vector_type(4))) float f32x4;
typedef __attribute__((ext_vector_type(4))) unsigned short us4;

__device__ __forceinline__ unsigned short bf16rne(float f){
  unsigned u = __float_as_uint(f);
  unsigned r = (u + 0x7FFFu + ((u>>16)&1u)) >> 16;
  return (unsigned short)r;
}
__device__ __forceinline__ float bf16tof(unsigned short h){
  return __uint_as_float((unsigned)h << 16);
}
// async global->LDS, 16B per lane; LDS dest = wave-uniform base + lane*16
__device__ __forceinline__ void gload16(const void* g, void* l){
  __builtin_amdgcn_global_load_lds(
      (const __attribute__((address_space(1))) void*)g,
      (__attribute__((address_space(3))) void*)l, 16, 0, 0);
}

// ---- X pre-convert: f32 [8192][1024] -> bf16 hi/lo MFMA-fragment image ----
__global__ __launch_bounds__(256) void xconv_kernel(
    const float* __restrict__ X,
    unsigned short* __restrict__ Xth, unsigned short* __restrict__ Xtl)
{
  const int kt = blockIdx.x & 31, mb = blockIdx.x >> 5;
  const int tid = threadIdx.x;
  const int unit = tid & 127, half = tid >> 7;
  const int g = unit >> 5, row = unit & 31;
  const float* src = X + (size_t)(mb*32 + row)*DM_ + kt*32 + g*8;
  float4 a = *reinterpret_cast<const float4*>(src);
  float4 b = *reinterpret_cast<const float4*>(src + 4);
  unsigned short* dst = (half ? Xtl : Xth) + ((size_t)(mb*32 + kt)*128 + unit)*8;
  if(half == 0){
    us4 h0 = {bf16rne(a.x),bf16rne(a.y),bf16rne(a.z),bf16rne(a.w)};
    us4 h1 = {bf16rne(b.x),bf16rne(b.y),bf16rne(b.z),bf16rne(b.w)};
    *(us4*)dst = h0; *(us4*)(dst+4) = h1;
  } else {
    us4 l0 = {bf16rne(a.x - bf16tof(bf16rne(a.x))), bf16rne(a.y - bf16tof(bf16rne(a.y))),
              bf16rne(a.z - bf16tof(bf16rne(a.z))), bf16rne(a.w - bf16tof(bf16rne(a.w)))};
    us4 l1 = {bf16rne(b.x - bf16tof(bf16rne(b.x))), bf16rne(b.y - bf16tof(bf16rne(b.y))),
              bf16rne(b.z - bf16tof(bf16rne(b.z))), bf16rne(b.w - bf16tof(bf16rne(b.w)))};
    *(us4*)dst = l0; *(us4*)(dst+4) = l1;
  }
}

// ---- W pre-convert: f32 [1024][128] -> bf16 hi/lo, pre-tiled [32 t][col][40] ----
__global__ __launch_bounds__(256) void wconv_kernel(
    const float* __restrict__ Wq, const float* __restrict__ Wk, const float* __restrict__ Wv,
    unsigned short* __restrict__ Wth, unsigned short* __restrict__ Wtl)
{
  const int t = blockIdx.x;       // k-tile 0..31
  const int which = blockIdx.y;   // 0..2
  const float* W = (which==0) ? Wq : ((which==1) ? Wk : Wv);
  const int tid = threadIdx.x;
  const size_t obase = ((size_t)which*32 + t)*5120;
  #pragma unroll
  for(int it=0; it<2; ++it){
    int idx = tid + 256*it;       // 0..511 -> (col, g)
    int col = idx & 127, g = idx >> 7;
    unsigned short hs[8], ls[8];
    #pragma unroll
    for(int j=0;j<8;j++){
      float f = W[(size_t)(t*32 + g*8 + j)*DK_ + col];
      unsigned short h = bf16rne(f);
      hs[j] = h;
      ls[j] = bf16rne(f - bf16tof(h));
    }
    size_t o = obase + (size_t)col*40 + g*8;
    *(us4*)&Wth[o]   = us4{hs[0],hs[1],hs[2],hs[3]};
    *(us4*)&Wth[o+4] = us4{hs[4],hs[5],hs[6],hs[7]};
    *(us4*)&Wtl[o]   = us4{ls[0],ls[1],ls[2],ls[3]};
    *(us4*)&Wtl[o+4] = us4{ls[4],ls[5],ls[6],ls[7]};
  }
}

// ---- QKV GEMM v9: bf16x3 MFMA for Q,K; bf16 hi-only for V (1 MFMA, half staging) ----
__global__ __launch_bounds__(256) void qkv_mfma_kernel(
    const unsigned short* __restrict__ Xth, const unsigned short* __restrict__ Xtl,
    const unsigned short* __restrict__ Wth, const unsigned short* __restrict__ Wtl,
    unsigned short* __restrict__ Qh, unsigned short* __restrict__ Ql,
    unsigned short* __restrict__ Kh, unsigned short* __restrict__ Kl,
    unsigned short* __restrict__ Vth)
{
  __shared__ __align__(16) unsigned char smem[49152];
  const int tid = threadIdx.x;
  const int w = tid >> 6, lane = tid & 63;
  const int l15 = lane & 15, g = lane >> 4;
  const int which = blockIdx.y;
  const bool vOnly = (which == 2);
  const int m0 = blockIdx.x * 32;
  const int mb = blockIdx.x;
  const unsigned char* Wh8 = (const unsigned char*)(Wth + (size_t)which*32*5120);
  const unsigned char* Wl8 = (const unsigned char*)(Wtl + (size_t)which*32*5120);
  const unsigned short* Asrc = ((w < 2) ? Xth : Xtl) + (size_t)(mb*32)*1024 + (w & 1)*512 + lane*8;
  const unsigned Adst = (unsigned)((w & 1)*1024) + ((w < 2) ? 0u : 2048u);
  const bool aSkip = (vOnly && w >= 2);          // V pass: no X-lo staging

  if(!aSkip) gload16(Asrc, smem + Adst);
  #pragma unroll
  for(int ii=0; ii<5; ++ii){
    int i = w + 4*ii;
    if(vOnly && i >= 10) continue;               // V pass: no W-lo staging
    const unsigned char* src = (i<10) ? (Wh8 + i*1024) : (Wl8 + (i-10)*1024);
    unsigned dst = 8192u + ((i<10) ? (unsigned)i*1024u : 10240u + (unsigned)(i-10)*1024u);
    gload16(src + lane*16, smem + dst);
  }

  f32x4 acc[4] = {f32x4{0,0,0,0},f32x4{0,0,0,0},f32x4{0,0,0,0},f32x4{0,0,0,0}};
  const int r = w >> 1, c0 = (w & 1)*4;
  const int aoff = (g*32 + r*16 + l15)*8;
  int buf = 0;
  for(int t=0; t<32; ++t){
    __syncthreads();
    if(t+1 < 32){
      if(!aSkip) gload16(Asrc + (size_t)(t+1)*1024, smem + (buf^1)*4096 + Adst);
      const unsigned char* WhT = Wh8 + (size_t)(t+1)*10240;
      const unsigned char* WlT = Wl8 + (size_t)(t+1)*10240;
      unsigned bbase = 8192u + (unsigned)(buf^1)*20480u;
      #pragma unroll
      for(int ii=0; ii<5; ++ii){
        int i = w + 4*ii;
        if(vOnly && i >= 10) continue;
        const unsigned char* src = (i<10) ? (WhT + i*1024) : (WlT + (i-10)*1024);
        unsigned dst = bbase + ((i<10) ? (unsigned)i*1024u : 10240u + (unsigned)(i-10)*1024u);
        gload16(src + lane*16, smem + dst);
      }
    }
    const unsigned short* Ab = (const unsigned short*)(smem + buf*4096);
    const unsigned short* Bhc = (const unsigned short*)(smem + 8192 + buf*20480);
    const unsigned short* Blc = Bhc + 5120;
    short8 ah = *(const short8*)&Ab[aoff];
    if(vOnly){
      #pragma unroll
      for(int c=0;c<4;c++){
        int boff = ((c0+c)*16 + l15)*40 + g*8;
        short8 bh = *(const short8*)&Bhc[boff];
        acc[c] = __builtin_amdgcn_mfma_f32_16x16x32_bf16(ah, bh, acc[c], 0, 0, 0);
      }
    } else {
      short8 al = *(const short8*)&Ab[1024 + aoff];
      #pragma unroll
      for(int c=0;c<4;c++){
        int boff = ((c0+c)*16 + l15)*40 + g*8;
        short8 bh = *(const short8*)&Bhc[boff];
        short8 bl = *(const short8*)&Blc[boff];
        acc[c] = __builtin_amdgcn_mfma_f32_16x16x32_bf16(ah, bh, acc[c], 0, 0, 0);
        acc[c] = __builtin_amdgcn_mfma_f32_16x16x32_bf16(ah, bl, acc[c], 0, 0, 0);
        acc[c] = __builtin_amdgcn_mfma_f32_16x16x32_bf16(al, bh, acc[c], 0, 0, 0);
      }
    }
    buf ^= 1;
  }
  const int b = m0 >> 11;
  const int orow0 = g*4;
  if(which != 2){
    unsigned short* Oh = (which==0) ? Qh : Kh;
    unsigned short* Ol = (which==0) ? Ql : Kl;
    #pragma unroll
    for(int c=0;c<4;c++){
      int col = (c0+c)*16 + l15;
      #pragma unroll
      for(int j=0;j<4;j++){
        float f = acc[c][j];
        unsigned short h = bf16rne(f);
        unsigned short lo = bf16rne(f - bf16tof(h));
        size_t o = (size_t)(m0 + r*16 + orow0 + j)*DK_ + col;
        Oh[o] = h; Ol[o] = lo;
      }
    }
  } else {
    __syncthreads();
    float* Tmp = (float*)smem;                 // [32][133]
    #pragma unroll
    for(int c=0;c<4;c++){
      int col = (c0+c)*16 + l15;
      #pragma unroll
      for(int j=0;j<4;j++)
        Tmp[(r*16 + orow0 + j)*133 + col] = acc[c][j];
    }
    __syncthreads();
    const int s0 = m0 & (S_-1);
    #pragma unroll
    for(int l2=0;l2<16;l2++){
      int p = tid + 256*l2;
      int d = p >> 5, rr = p & 31;
      Vth[(size_t)(b*DK_ + d)*S_ + s0 + rr] = bf16rne(Tmp[rr*133 + d]);
    }
  }
}

// ---- scores via bf16x3 MFMA: staging via gload16 (pre-swizzled source, linear LDS) ----
__global__ __launch_bounds__(256) void scores_kernel(
    const unsigned short* __restrict__ Qh, const unsigned short* __restrict__ Ql,
    const unsigned short* __restrict__ Kh, const unsigned short* __restrict__ Kl,
    float* __restrict__ attn, float* __restrict__ cmaxpart, float* __restrict__ csumpart)
{
  const int tj = blockIdx.x, ti = blockIdx.y, b = blockIdx.z;
  const int tid = threadIdx.x;
  const int q0 = ti*64, k0 = tj*64;
  if(tj > ti){                                 // upper triangle: zero-fill tile
    float4 z = {0.f,0.f,0.f,0.f};
    #pragma unroll
    for(int l=0;l<4;l++){
      int p = tid + 256*l;
      int r = p >> 4, c = (p & 15) << 2;
      *reinterpret_cast<float4*>(&attn[((size_t)(b*S_) + q0 + r)*S_ + k0 + c]) = z;
    }
    return;
  }
  // 4 tiles x [64][64] shorts linear (8KB each, swizzled content) = 32KB
  __shared__ __align__(16) unsigned short sm[16384];
  __shared__ float cred[16][64];
  __shared__ float csum[16][64];
  __shared__ float maxsh[64];
  const int w = tid >> 6, lane = tid & 63, l15 = lane & 15, g = lane >> 4;
  const unsigned short* tsrc[4] = {Qh, Ql, Kh, Kl};
  f32x4 acc[4] = {f32x4{0,0,0,0},f32x4{0,0,0,0},f32x4{0,0,0,0},f32x4{0,0,0,0}};
  for(int kh=0; kh<2; ++kh){
    __syncthreads();                           // prev compute readers done
    // stage 2048 16B-units: chunk c = w + 4*i holds units c*64 + lane
    #pragma unroll
    for(int i=0;i<8;i++){
      int c = w + 4*i;                         // 0..31
      int uu = c*64 + lane;                    // 0..2047
      int tile = uu >> 9;                      // 0..3
      int u = uu & 511;
      int row = u >> 3, sl = u & 7;
      int ssl = sl ^ (row & 7);                // pre-swizzled source slot
      int gr = (tile < 2) ? (q0 + row) : (k0 + row);
      gload16(tsrc[tile] + (size_t)(b*S_ + gr)*DK_ + kh*64 + ssl*8,
              (unsigned char*)sm + (unsigned)c*1024u);
    }
    __syncthreads();                           // drains gloads
    const unsigned short* Qhs = sm;
    const unsigned short* Qls = sm + 4096;
    const unsigned short* Khs = sm + 8192;
    const unsigned short* Kls = sm + 12288;
    #pragma unroll
    for(int ks=0; ks<2; ++ks){                 // 2 x K=32 per half
      int arow = w*16 + l15;
      int ao = arow*64 + (((ks*4 + g) ^ (arow & 7)) << 3);
      short8 ah = *(const short8*)&Qhs[ao];
      short8 al = *(const short8*)&Qls[ao];
      #pragma unroll
      for(int c=0;c<4;c++){
        int brow = c*16 + l15;
        int bo = brow*64 + (((ks*4 + g) ^ (brow & 7)) << 3);
        short8 bh = *(const short8*)&Khs[bo];
        short8 bl = *(const short8*)&Kls[bo];
        acc[c] = __builtin_amdgcn_mfma_f32_16x16x32_bf16(ah, bh, acc[c], 0, 0, 0);
        acc[c] = __builtin_amdgcn_mfma_f32_16x16x32_bf16(ah, bl, acc[c], 0, 0, 0);
        acc[c] = __builtin_amdgcn_mfma_f32_16x16x32_bf16(al, bh, acc[c], 0, 0, 0);
      }
    }
  }
  const bool full = (ti > tj);
  const int qbase = q0 + w*16 + g*4;
  #pragma unroll
  for(int c=0;c<4;c++){
    int kcol = k0 + c*16 + l15;
    float cm = -INFINITY;
    #pragma unroll
    for(int j=0;j<4;j++){
      int q = qbase + j;
      float s = acc[c][j]*SCALE;
      bool valid = full || (q >= kcol);
      attn[((size_t)(b*S_) + q)*S_ + kcol] = valid ? s : 0.f;
      if(valid) cm = fmaxf(cm, s);
    }
    cred[w*4 + g][c*16 + l15] = cm;
  }
  __syncthreads();
  if(tid < 64){
    float m = cred[0][tid];
    #pragma unroll
    for(int gg=1;gg<16;gg++) m = fmaxf(m, cred[gg][tid]);
    maxsh[tid] = m;
    cmaxpart[((size_t)(b*S_) + k0 + tid)*32 + ti] = m;
  }
  __syncthreads();
  #pragma unroll
  for(int c=0;c<4;c++){
    int col = c*16 + l15;
    int kcol = k0 + col;
    float mcol = maxsh[col];
    float ps = 0.f;
    #pragma unroll
    for(int j=0;j<4;j++){
      int q = qbase + j;
      bool valid = full || (q >= kcol);
      if(valid) ps += __expf(acc[c][j]*SCALE - mcol);
    }
    csum[w*4 + g][col] = ps;
  }
  __syncthreads();
  if(tid < 64){
    float s = 0.f;
    #pragma unroll
    for(int gg=0;gg<16;gg++) s += csum[gg][tid];
    csumpart[((size_t)(b*S_) + k0 + tid)*32 + ti] = s;
  }
}

// ---- column flash-reduce in fixed tile order -> final max + reciprocal sums ----
__global__ __launch_bounds__(256) void colreduce_kernel(
    const float* __restrict__ cmaxpart, const float* __restrict__ csumpart,
    float* __restrict__ cmaxf, float* __restrict__ rcol)
{
  int i = blockIdx.x*256 + threadIdx.x;  // 0..8191 = b*S + k
  if(i >= B_*S_) return;
  int k = i & (S_-1);
  int t0 = k >> 6;
  float M = -INFINITY;
  for(int t=t0; t<32; t++) M = fmaxf(M, cmaxpart[(size_t)i*32 + t]);
  float s = 0.f;
  for(int t=t0; t<32; t++) s += csumpart[(size_t)i*32 + t] * __expf(cmaxpart[(size_t)i*32 + t] - M);
  cmaxf[i] = M;
  rcol[i] = 1.0f / s;
}

// ---- fused PV: V staged via gload16 (pre-swizzled source, linear LDS); P hi/lo x V hi ----
__global__ __launch_bounds__(256) void pv_kernel(
    float* __restrict__ attn, const float* __restrict__ cmaxf,
    const float* __restrict__ rcol,
    const unsigned short* __restrict__ Vth,
    float* __restrict__ part, int ns)
{
  // shorts: Ahs [64][72] @0, Als @4608, VhsL linear [128][64] @9216  -> 34816 B
  __shared__ __align__(16) unsigned short sm[17408];
  unsigned short* Ahs = sm;
  unsigned short* Als = sm + 4608;
  unsigned short* VhsL = sm + 9216;
  const int b = blockIdx.z, tid = threadIdx.x;
  const int sp = blockIdx.y;
  const int w = tid >> 6, lane = tid & 63, l15 = lane & 15, g = lane >> 4;
  const int t = 31 - (int)blockIdx.x;              // heavy tiles first
  const int q0 = t*64;
  const int nch = t + 1;
  const int lo = (sp*nch)/ns, hi = ((sp+1)*nch)/ns;
  f32x4 acc[8] = {f32x4{0,0,0,0},f32x4{0,0,0,0},f32x4{0,0,0,0},f32x4{0,0,0,0},
                  f32x4{0,0,0,0},f32x4{0,0,0,0},f32x4{0,0,0,0},f32x4{0,0,0,0}};
  const int er = tid >> 4, ekq = (tid & 15) << 2;
  const unsigned short* Vb = Vth + (size_t)(b*DK_)*S_;
  for(int ch=lo; ch<hi; ++ch){
    const int k0c = ch*64;
    float4 m4 = *reinterpret_cast<const float4*>(&cmaxf[b*S_ + k0c + ekq]);
    float4 r4 = *reinterpret_cast<const float4*>(&rcol[b*S_ + k0c + ekq]);
    const bool diag = (ch == t);
    __syncthreads();                               // prev MFMA readers done
    // issue V stage FIRST (async; flies under the exp phase; drained at next barrier)
    #pragma unroll
    for(int v=0; v<4; ++v){
      int idx = v*256 + tid;                       // 16B unit 0..1023
      int row = idx >> 3, sl = idx & 7;
      int ssl = sl ^ (row & 7);                    // pre-swizzled source slot
      gload16(Vb + (size_t)row*S_ + k0c + ssl*8, (unsigned char*)VhsL + idx*16);
    }
    #pragma unroll
    for(int rr=0; rr<4; ++rr){
      int row = rr*16 + er;
      size_t ea = ((size_t)(b*S_) + q0 + row)*S_ + k0c + ekq;
      float4 sv = *reinterpret_cast<const float4*>(&attn[ea]);
      float p0 = __expf(sv.x - m4.x)*r4.x;
      float p1 = __expf(sv.y - m4.y)*r4.y;
      float p2 = __expf(sv.z - m4.z)*r4.z;
      float p3 = __expf(sv.w - m4.w)*r4.w;
      if(diag){
        p0 = (row >= ekq+0) ? p0 : 0.f;
        p1 = (row >= ekq+1) ? p1 : 0.f;
        p2 = (row >= ekq+2) ? p2 : 0.f;
        p3 = (row >= ekq+3) ? p3 : 0.f;
      }
      float4 pv4 = {p0,p1,p2,p3};
      *reinterpret_cast<float4*>(&attn[ea]) = pv4; // normalized attention (final output)
      unsigned short h0=bf16rne(p0), h1=bf16rne(p1), h2=bf16rne(p2), h3=bf16rne(p3);
      *(us4*)&Ahs[row*72 + ekq] = us4{h0,h1,h2,h3};
      *(us4*)&Als[row*72 + ekq] = us4{ bf16rne(p0-bf16tof(h0)), bf16rne(p1-bf16tof(h1)),
                                       bf16rne(p2-bf16tof(h2)), bf16rne(p3-bf16tof(h3)) };
    }
    __syncthreads();                               // drains gloads + ds_writes
    #pragma unroll
    for(int ks=0; ks<2; ++ks){
      int ao = (w*16 + l15)*72 + ks*32 + g*8;
      short8 ah = *(const short8*)&Ahs[ao];
      short8 al = *(const short8*)&Als[ao];
      #pragma unroll
      for(int c=0;c<8;c++){
        int row = c*16 + l15;
        int bo = row*64 + (((ks*4 + g) ^ (l15 & 7)) << 3);   // un-swizzle on read
        short8 bh = *(const short8*)&VhsL[bo];
        acc[c] = __builtin_amdgcn_mfma_f32_16x16x32_bf16(ah, bh, acc[c], 0, 0, 0);
        acc[c] = __builtin_amdgcn_mfma_f32_16x16x32_bf16(al, bh, acc[c], 0, 0, 0);
      }
    }
  }
  float* pout = part + (((size_t)(sp*B_ + b))*S_ + q0)*DK_;
  #pragma unroll
  for(int c=0;c<8;c++){
    #pragma unroll
    for(int j=0;j<4;j++){
      int qrow = w*16 + g*4 + j;
      pout[(size_t)qrow*DK_ + c*16 + l15] = acc[c][j];
    }
  }
}

// ---- sum split-K partials in fixed order ----
__global__ __launch_bounds__(256) void pvreduce_kernel(
    const float* __restrict__ part, float* __restrict__ out, int ns)
{
  const int N4 = (B_*S_*DK_)/4;   // 262144 float4
  int i = blockIdx.x*256 + threadIdx.x;
  if(i >= N4) return;
  const float4* p = reinterpret_cast<const float4*>(part);
  float4 a = p[i];
  for(int s=1; s<ns; ++s){
    float4 q = p[(size_t)s*N4 + i];
    a.x += q.x; a.y += q.y; a.z += q.z; a.w += q.w;
  }
  reinterpret_cast<float4*>(out)[i] = a;
}

extern "C" void kernel_launch(void* const* d_in, const int* in_sizes, int n_in,
                              void* d_out, int out_size, void* d_ws, size_t ws_size,
                              hipStream_t stream)
{
  (void)in_sizes; (void)n_in; (void)out_size;
  const float* X  = (const float*)d_in[0];
  const float* Wq = (const float*)d_in[1];
  const float* Wk = (const float*)d_in[2];
  const float* Wv = (const float*)d_in[3];
  float* out  = (float*)d_out;
  float* attn = out + (size_t)B_*S_*DK_;            // attention output region (64MB)

  // X bf16 hi/lo images live INSIDE the attn region (dead once scores runs)
  unsigned short* Xth = (unsigned short*)attn;            // 16MB
  unsigned short* Xtl = Xth + (size_t)8388608;            // 16MB

  float* ws = (float*)d_ws;
  float* cmaxf    = ws;                              // [8192]
  float* rcol     = ws + 8192;                       // [8192]
  float* csumpart = ws + 16384;                      // [8192*32]
  float* cmaxpart = ws + 278528;                     // [8192*32]
  unsigned short* Wth = (unsigned short*)(ws + 540672);   // [3][32][5120] shorts
  unsigned short* Wtl = (unsigned short*)(ws + 786432);
  unsigned short* Qh  = (unsigned short*)(ws + 1032192);  // [8192][128] shorts each
  unsigned short* Ql  = (unsigned short*)(ws + 1556480);
  unsigned short* Kh  = (unsigned short*)(ws + 2080768);
  unsigned short* Kl  = (unsigned short*)(ws + 2605056);
  unsigned short* Vth = (unsigned short*)(ws + 3129344);  // [4][128][2048] shorts
  const size_t base = 3653632;                       // floats used so far
  float* part    = ws + base;                        // [ns][4][2048][128]

  int ns = 8;
  if(ws_size < (base + (size_t)8*1048576)*sizeof(float)) ns = 4;
  if(ws_size < (base + (size_t)4*1048576)*sizeof(float)) ns = 2;
  if(ws_size < (base + (size_t)2*1048576)*sizeof(float)) ns = 1;

  xconv_kernel<<<dim3(8192), dim3(256), 0, stream>>>(X, Xth, Xtl);
  wconv_kernel<<<dim3(32,3), dim3(256), 0, stream>>>(Wq, Wk, Wv, Wth, Wtl);
  qkv_mfma_kernel<<<dim3(256,3), dim3(256), 0, stream>>>(Xth, Xtl, Wth, Wtl, Qh, Ql, Kh, Kl, Vth);
  scores_kernel<<<dim3(32,32,4), dim3(256), 0, stream>>>(Qh, Ql, Kh, Kl, attn, cmaxpart, csumpart);
  colreduce_kernel<<<dim3(32), dim3(256), 0, stream>>>(cmaxpart, csumpart, cmaxf, rcol);
  pv_kernel<<<dim3(32,ns,4), dim3(256), 0, stream>>>(attn, cmaxf, rcol, Vth, part, ns);
  pvreduce_kernel<<<dim3(1024), dim3(256), 0, stream>>>(part, out, ns);
}

// Round 20
// 104.946 us; speedup vs baseline: 1.1601x; 1.0667x over previous
//
#include <hip/hip_runtime.h>
#include <math.h>
#include <stdint.h>

#define B_ 4
#define S_ 2048
#define DM_ 1024
#define DK_ 128

static constexpr float SCALE = 0.08838834764831845f; // 1/sqrt(128)

typedef __attribute__((ext_vector_type(8))) short short8;
typedef __attribute__((ext_vector_type(4))) float f32x4;
typedef __attribute__((ext_vector_type(4))) unsigned short us4;

__device__ __forceinline__ unsigned short bf16rne(float f){
  unsigned u = __float_as_uint(f);
  unsigned r = (u + 0x7FFFu + ((u>>16)&1u)) >> 16;
  return (unsigned short)r;
}
__device__ __forceinline__ float bf16tof(unsigned short h){
  return __uint_as_float((unsigned)h << 16);
}
// async global->LDS, 16B per lane; LDS dest = wave-uniform base + lane*16
__device__ __forceinline__ void gload16(const void* g, void* l){
  __builtin_amdgcn_global_load_lds(
      (const __attribute__((address_space(1))) void*)g,
      (__attribute__((address_space(3))) void*)l, 16, 0, 0);
}

// ---- fused pre-convert: X (blocks 0..8191) and W (blocks 8192..8287) -> bf16 hi/lo images ----
__global__ __launch_bounds__(256) void conv_kernel(
    const float* __restrict__ X,
    const float* __restrict__ Wq, const float* __restrict__ Wk, const float* __restrict__ Wv,
    unsigned short* __restrict__ Xth, unsigned short* __restrict__ Xtl,
    unsigned short* __restrict__ Wth, unsigned short* __restrict__ Wtl)
{
  const int bx = blockIdx.x;
  const int tid = threadIdx.x;
  if(bx < 8192){
    const int kt = bx & 31, mb = bx >> 5;
    const int unit = tid & 127, half = tid >> 7;
    const int g = unit >> 5, row = unit & 31;
    const float* src = X + (size_t)(mb*32 + row)*DM_ + kt*32 + g*8;
    float4 a = *reinterpret_cast<const float4*>(src);
    float4 b = *reinterpret_cast<const float4*>(src + 4);
    unsigned short* dst = (half ? Xtl : Xth) + ((size_t)(mb*32 + kt)*128 + unit)*8;
    if(half == 0){
      us4 h0 = {bf16rne(a.x),bf16rne(a.y),bf16rne(a.z),bf16rne(a.w)};
      us4 h1 = {bf16rne(b.x),bf16rne(b.y),bf16rne(b.z),bf16rne(b.w)};
      *(us4*)dst = h0; *(us4*)(dst+4) = h1;
    } else {
      us4 l0 = {bf16rne(a.x - bf16tof(bf16rne(a.x))), bf16rne(a.y - bf16tof(bf16rne(a.y))),
                bf16rne(a.z - bf16tof(bf16rne(a.z))), bf16rne(a.w - bf16tof(bf16rne(a.w)))};
      us4 l1 = {bf16rne(b.x - bf16tof(bf16rne(b.x))), bf16rne(b.y - bf16tof(bf16rne(b.y))),
                bf16rne(b.z - bf16tof(bf16rne(b.z))), bf16rne(b.w - bf16tof(bf16rne(b.w)))};
      *(us4*)dst = l0; *(us4*)(dst+4) = l1;
    }
  } else {
    const int wb = bx - 8192;                 // 0..95
    const int which = wb >> 5, t = wb & 31;
    const float* W = (which==0) ? Wq : ((which==1) ? Wk : Wv);
    const size_t obase = ((size_t)which*32 + t)*5120;
    #pragma unroll
    for(int it=0; it<2; ++it){
      int idx = tid + 256*it;                 // 0..511 -> (col, g)
      int col = idx & 127, g = idx >> 7;
      unsigned short hs[8], ls[8];
      #pragma unroll
      for(int j=0;j<8;j++){
        float f = W[(size_t)(t*32 + g*8 + j)*DK_ + col];
        unsigned short h = bf16rne(f);
        hs[j] = h;
        ls[j] = bf16rne(f - bf16tof(h));
      }
      size_t o = obase + (size_t)col*40 + g*8;
      *(us4*)&Wth[o]   = us4{hs[0],hs[1],hs[2],hs[3]};
      *(us4*)&Wth[o+4] = us4{hs[4],hs[5],hs[6],hs[7]};
      *(us4*)&Wtl[o]   = us4{ls[0],ls[1],ls[2],ls[3]};
      *(us4*)&Wtl[o+4] = us4{ls[4],ls[5],ls[6],ls[7]};
    }
  }
}

// ---- QKV GEMM v9: bf16x3 MFMA for Q,K; bf16 hi-only for V (1 MFMA, half staging) ----
__global__ __launch_bounds__(256) void qkv_mfma_kernel(
    const unsigned short* __restrict__ Xth, const unsigned short* __restrict__ Xtl,
    const unsigned short* __restrict__ Wth, const unsigned short* __restrict__ Wtl,
    unsigned short* __restrict__ Qh, unsigned short* __restrict__ Ql,
    unsigned short* __restrict__ Kh, unsigned short* __restrict__ Kl,
    unsigned short* __restrict__ Vth)
{
  __shared__ __align__(16) unsigned char smem[49152];
  const int tid = threadIdx.x;
  const int w = tid >> 6, lane = tid & 63;
  const int l15 = lane & 15, g = lane >> 4;
  const int which = blockIdx.y;
  const bool vOnly = (which == 2);
  const int m0 = blockIdx.x * 32;
  const int mb = blockIdx.x;
  const unsigned char* Wh8 = (const unsigned char*)(Wth + (size_t)which*32*5120);
  const unsigned char* Wl8 = (const unsigned char*)(Wtl + (size_t)which*32*5120);
  const unsigned short* Asrc = ((w < 2) ? Xth : Xtl) + (size_t)(mb*32)*1024 + (w & 1)*512 + lane*8;
  const unsigned Adst = (unsigned)((w & 1)*1024) + ((w < 2) ? 0u : 2048u);
  const bool aSkip = (vOnly && w >= 2);          // V pass: no X-lo staging

  if(!aSkip) gload16(Asrc, smem + Adst);
  #pragma unroll
  for(int ii=0; ii<5; ++ii){
    int i = w + 4*ii;
    if(vOnly && i >= 10) continue;               // V pass: no W-lo staging
    const unsigned char* src = (i<10) ? (Wh8 + i*1024) : (Wl8 + (i-10)*1024);
    unsigned dst = 8192u + ((i<10) ? (unsigned)i*1024u : 10240u + (unsigned)(i-10)*1024u);
    gload16(src + lane*16, smem + dst);
  }

  f32x4 acc[4] = {f32x4{0,0,0,0},f32x4{0,0,0,0},f32x4{0,0,0,0},f32x4{0,0,0,0}};
  const int r = w >> 1, c0 = (w & 1)*4;
  const int aoff = (g*32 + r*16 + l15)*8;
  int buf = 0;
  for(int t=0; t<32; ++t){
    __syncthreads();
    if(t+1 < 32){
      if(!aSkip) gload16(Asrc + (size_t)(t+1)*1024, smem + (buf^1)*4096 + Adst);
      const unsigned char* WhT = Wh8 + (size_t)(t+1)*10240;
      const unsigned char* WlT = Wl8 + (size_t)(t+1)*10240;
      unsigned bbase = 8192u + (unsigned)(buf^1)*20480u;
      #pragma unroll
      for(int ii=0; ii<5; ++ii){
        int i = w + 4*ii;
        if(vOnly && i >= 10) continue;
        const unsigned char* src = (i<10) ? (WhT + i*1024) : (WlT + (i-10)*1024);
        unsigned dst = bbase + ((i<10) ? (unsigned)i*1024u : 10240u + (unsigned)(i-10)*1024u);
        gload16(src + lane*16, smem + dst);
      }
    }
    const unsigned short* Ab = (const unsigned short*)(smem + buf*4096);
    const unsigned short* Bhc = (const unsigned short*)(smem + 8192 + buf*20480);
    const unsigned short* Blc = Bhc + 5120;
    short8 ah = *(const short8*)&Ab[aoff];
    if(vOnly){
      #pragma unroll
      for(int c=0;c<4;c++){
        int boff = ((c0+c)*16 + l15)*40 + g*8;
        short8 bh = *(const short8*)&Bhc[boff];
        acc[c] = __builtin_amdgcn_mfma_f32_16x16x32_bf16(ah, bh, acc[c], 0, 0, 0);
      }
    } else {
      short8 al = *(const short8*)&Ab[1024 + aoff];
      #pragma unroll
      for(int c=0;c<4;c++){
        int boff = ((c0+c)*16 + l15)*40 + g*8;
        short8 bh = *(const short8*)&Bhc[boff];
        short8 bl = *(const short8*)&Blc[boff];
        acc[c] = __builtin_amdgcn_mfma_f32_16x16x32_bf16(ah, bh, acc[c], 0, 0, 0);
        acc[c] = __builtin_amdgcn_mfma_f32_16x16x32_bf16(ah, bl, acc[c], 0, 0, 0);
        acc[c] = __builtin_amdgcn_mfma_f32_16x16x32_bf16(al, bh, acc[c], 0, 0, 0);
      }
    }
    buf ^= 1;
  }
  const int b = m0 >> 11;
  const int orow0 = g*4;
  if(which != 2){
    unsigned short* Oh = (which==0) ? Qh : Kh;
    unsigned short* Ol = (which==0) ? Ql : Kl;
    #pragma unroll
    for(int c=0;c<4;c++){
      int col = (c0+c)*16 + l15;
      #pragma unroll
      for(int j=0;j<4;j++){
        float f = acc[c][j];
        unsigned short h = bf16rne(f);
        unsigned short lo = bf16rne(f - bf16tof(h));
        size_t o = (size_t)(m0 + r*16 + orow0 + j)*DK_ + col;
        Oh[o] = h; Ol[o] = lo;
      }
    }
  } else {
    __syncthreads();
    float* Tmp = (float*)smem;                 // [32][133]
    #pragma unroll
    for(int c=0;c<4;c++){
      int col = (c0+c)*16 + l15;
      #pragma unroll
      for(int j=0;j<4;j++)
        Tmp[(r*16 + orow0 + j)*133 + col] = acc[c][j];
    }
    __syncthreads();
    const int s0 = m0 & (S_-1);
    #pragma unroll
    for(int l2=0;l2<16;l2++){
      int p = tid + 256*l2;
      int d = p >> 5, rr = p & 31;
      Vth[(size_t)(b*DK_ + d)*S_ + s0 + rr] = bf16rne(Tmp[rr*133 + d]);
    }
  }
}

// ---- scores via bf16x3 MFMA: staging via gload16 (pre-swizzled source, linear LDS) ----
__global__ __launch_bounds__(256) void scores_kernel(
    const unsigned short* __restrict__ Qh, const unsigned short* __restrict__ Ql,
    const unsigned short* __restrict__ Kh, const unsigned short* __restrict__ Kl,
    float* __restrict__ attn, float* __restrict__ cmaxpart, float* __restrict__ csumpart)
{
  const int tj = blockIdx.x, ti = blockIdx.y, b = blockIdx.z;
  const int tid = threadIdx.x;
  const int q0 = ti*64, k0 = tj*64;
  if(tj > ti){                                 // upper triangle: zero-fill tile
    float4 z = {0.f,0.f,0.f,0.f};
    #pragma unroll
    for(int l=0;l<4;l++){
      int p = tid + 256*l;
      int r = p >> 4, c = (p & 15) << 2;
      *reinterpret_cast<float4*>(&attn[((size_t)(b*S_) + q0 + r)*S_ + k0 + c]) = z;
    }
    return;
  }
  // 4 tiles x [64][64] shorts linear (8KB each, swizzled content) = 32KB
  __shared__ __align__(16) unsigned short sm[16384];
  __shared__ float cred[16][64];
  __shared__ float csum[16][64];
  __shared__ float maxsh[64];
  const int w = tid >> 6, lane = tid & 63, l15 = lane & 15, g = lane >> 4;
  const unsigned short* tsrc[4] = {Qh, Ql, Kh, Kl};
  f32x4 acc[4] = {f32x4{0,0,0,0},f32x4{0,0,0,0},f32x4{0,0,0,0},f32x4{0,0,0,0}};
  for(int kh=0; kh<2; ++kh){
    __syncthreads();                           // prev compute readers done
    #pragma unroll
    for(int i=0;i<8;i++){
      int c = w + 4*i;                         // 0..31
      int uu = c*64 + lane;                    // 0..2047
      int tile = uu >> 9;                      // 0..3
      int u = uu & 511;
      int row = u >> 3, sl = u & 7;
      int ssl = sl ^ (row & 7);                // pre-swizzled source slot
      int gr = (tile < 2) ? (q0 + row) : (k0 + row);
      gload16(tsrc[tile] + (size_t)(b*S_ + gr)*DK_ + kh*64 + ssl*8,
              (unsigned char*)sm + (unsigned)c*1024u);
    }
    __syncthreads();                           // drains gloads
    const unsigned short* Qhs = sm;
    const unsigned short* Qls = sm + 4096;
    const unsigned short* Khs = sm + 8192;
    const unsigned short* Kls = sm + 12288;
    #pragma unroll
    for(int ks=0; ks<2; ++ks){                 // 2 x K=32 per half
      int arow = w*16 + l15;
      int ao = arow*64 + (((ks*4 + g) ^ (arow & 7)) << 3);
      short8 ah = *(const short8*)&Qhs[ao];
      short8 al = *(const short8*)&Qls[ao];
      #pragma unroll
      for(int c=0;c<4;c++){
        int brow = c*16 + l15;
        int bo = brow*64 + (((ks*4 + g) ^ (brow & 7)) << 3);
        short8 bh = *(const short8*)&Khs[bo];
        short8 bl = *(const short8*)&Kls[bo];
        acc[c] = __builtin_amdgcn_mfma_f32_16x16x32_bf16(ah, bh, acc[c], 0, 0, 0);
        acc[c] = __builtin_amdgcn_mfma_f32_16x16x32_bf16(ah, bl, acc[c], 0, 0, 0);
        acc[c] = __builtin_amdgcn_mfma_f32_16x16x32_bf16(al, bh, acc[c], 0, 0, 0);
      }
    }
  }
  const bool full = (ti > tj);
  const int qbase = q0 + w*16 + g*4;
  #pragma unroll
  for(int c=0;c<4;c++){
    int kcol = k0 + c*16 + l15;
    float cm = -INFINITY;
    #pragma unroll
    for(int j=0;j<4;j++){
      int q = qbase + j;
      float s = acc[c][j]*SCALE;
      bool valid = full || (q >= kcol);
      attn[((size_t)(b*S_) + q)*S_ + kcol] = valid ? s : 0.f;
      if(valid) cm = fmaxf(cm, s);
    }
    cred[w*4 + g][c*16 + l15] = cm;
  }
  __syncthreads();
  if(tid < 64){
    float m = cred[0][tid];
    #pragma unroll
    for(int gg=1;gg<16;gg++) m = fmaxf(m, cred[gg][tid]);
    maxsh[tid] = m;
    cmaxpart[((size_t)(b*S_) + k0 + tid)*32 + ti] = m;
  }
  __syncthreads();
  #pragma unroll
  for(int c=0;c<4;c++){
    int col = c*16 + l15;
    int kcol = k0 + col;
    float mcol = maxsh[col];
    float ps = 0.f;
    #pragma unroll
    for(int j=0;j<4;j++){
      int q = qbase + j;
      bool valid = full || (q >= kcol);
      if(valid) ps += __expf(acc[c][j]*SCALE - mcol);
    }
    csum[w*4 + g][col] = ps;
  }
  __syncthreads();
  if(tid < 64){
    float s = 0.f;
    #pragma unroll
    for(int gg=0;gg<16;gg++) s += csum[gg][tid];
    csumpart[((size_t)(b*S_) + k0 + tid)*32 + ti] = s;
  }
}

// ---- column flash-reduce in fixed tile order -> final max + reciprocal sums ----
__global__ __launch_bounds__(256) void colreduce_kernel(
    const float* __restrict__ cmaxpart, const float* __restrict__ csumpart,
    float* __restrict__ cmaxf, float* __restrict__ rcol)
{
  int i = blockIdx.x*256 + threadIdx.x;  // 0..8191 = b*S + k
  if(i >= B_*S_) return;
  int k = i & (S_-1);
  int t0 = k >> 6;
  float M = -INFINITY;
  for(int t=t0; t<32; t++) M = fmaxf(M, cmaxpart[(size_t)i*32 + t]);
  float s = 0.f;
  for(int t=t0; t<32; t++) s += csumpart[(size_t)i*32 + t] * __expf(cmaxpart[(size_t)i*32 + t] - M);
  cmaxf[i] = M;
  rcol[i] = 1.0f / s;
}

// ---- fused PV: V via swizzled gload16; P hi-only MFMA (attention output stays f32) ----
__global__ __launch_bounds__(256) void pv_kernel(
    float* __restrict__ attn, const float* __restrict__ cmaxf,
    const float* __restrict__ rcol,
    const unsigned short* __restrict__ Vth,
    float* __restrict__ part, int ns)
{
  // shorts: Ahs [64][72] @0 (4608), VhsL linear [128][64] @4608 (8192) -> 25600 B
  __shared__ __align__(16) unsigned short sm[12800];
  unsigned short* Ahs = sm;
  unsigned short* VhsL = sm + 4608;
  const int b = blockIdx.z, tid = threadIdx.x;
  const int sp = blockIdx.y;
  const int w = tid >> 6, lane = tid & 63, l15 = lane & 15, g = lane >> 4;
  const int t = 31 - (int)blockIdx.x;              // heavy tiles first
  const int q0 = t*64;
  const int nch = t + 1;
  const int lo = (sp*nch)/ns, hi = ((sp+1)*nch)/ns;
  if(lo >= hi) return;                             // empty split: writes skipped (pvreduce skips too)
  f32x4 acc[8] = {f32x4{0,0,0,0},f32x4{0,0,0,0},f32x4{0,0,0,0},f32x4{0,0,0,0},
                  f32x4{0,0,0,0},f32x4{0,0,0,0},f32x4{0,0,0,0},f32x4{0,0,0,0}};
  const int er = tid >> 4, ekq = (tid & 15) << 2;
  const unsigned short* Vb = Vth + (size_t)(b*DK_)*S_;
  for(int ch=lo; ch<hi; ++ch){
    const int k0c = ch*64;
    float4 m4 = *reinterpret_cast<const float4*>(&cmaxf[b*S_ + k0c + ekq]);
    float4 r4 = *reinterpret_cast<const float4*>(&rcol[b*S_ + k0c + ekq]);
    const bool diag = (ch == t);
    __syncthreads();                               // prev MFMA readers done
    // issue V stage FIRST (async; flies under the exp phase; drained at next barrier)
    #pragma unroll
    for(int v=0; v<4; ++v){
      int idx = v*256 + tid;                       // 16B unit 0..1023
      int row = idx >> 3, sl = idx & 7;
      int ssl = sl ^ (row & 7);                    // pre-swizzled source slot
      gload16(Vb + (size_t)row*S_ + k0c + ssl*8, (unsigned char*)VhsL + idx*16);
    }
    #pragma unroll
    for(int rr=0; rr<4; ++rr){
      int row = rr*16 + er;
      size_t ea = ((size_t)(b*S_) + q0 + row)*S_ + k0c + ekq;
      float4 sv = *reinterpret_cast<const float4*>(&attn[ea]);
      float p0 = __expf(sv.x - m4.x)*r4.x;
      float p1 = __expf(sv.y - m4.y)*r4.y;
      float p2 = __expf(sv.z - m4.z)*r4.z;
      float p3 = __expf(sv.w - m4.w)*r4.w;
      if(diag){
        p0 = (row >= ekq+0) ? p0 : 0.f;
        p1 = (row >= ekq+1) ? p1 : 0.f;
        p2 = (row >= ekq+2) ? p2 : 0.f;
        p3 = (row >= ekq+3) ? p3 : 0.f;
      }
      float4 pv4 = {p0,p1,p2,p3};
      *reinterpret_cast<float4*>(&attn[ea]) = pv4; // normalized attention (final output, f32)
      *(us4*)&Ahs[row*72 + ekq] = us4{bf16rne(p0),bf16rne(p1),bf16rne(p2),bf16rne(p3)};
    }
    __syncthreads();                               // drains gloads + ds_writes
    #pragma unroll
    for(int ks=0; ks<2; ++ks){
      int ao = (w*16 + l15)*72 + ks*32 + g*8;
      short8 ah = *(const short8*)&Ahs[ao];
      #pragma unroll
      for(int c=0;c<8;c++){
        int row = c*16 + l15;
        int bo = row*64 + (((ks*4 + g) ^ (l15 & 7)) << 3);   // un-swizzle on read
        short8 bh = *(const short8*)&VhsL[bo];
        acc[c] = __builtin_amdgcn_mfma_f32_16x16x32_bf16(ah, bh, acc[c], 0, 0, 0);
      }
    }
  }
  float* pout = part + (((size_t)(sp*B_ + b))*S_ + q0)*DK_;
  #pragma unroll
  for(int c=0;c<8;c++){
    #pragma unroll
    for(int j=0;j<4;j++){
      int qrow = w*16 + g*4 + j;
      pout[(size_t)qrow*DK_ + c*16 + l15] = acc[c][j];
    }
  }
}

// ---- sum split-K partials in fixed order, skipping empty splits ----
__global__ __launch_bounds__(256) void pvreduce_kernel(
    const float* __restrict__ part, float* __restrict__ out, int ns, int lns)
{
  const int N4 = (B_*S_*DK_)/4;   // 262144 float4
  int i = blockIdx.x*256 + threadIdx.x;
  if(i >= N4) return;
  int q = (i >> 5) & (S_-1);
  int nch = (q >> 6) + 1;
  const float4* p = reinterpret_cast<const float4*>(part);
  float4 a = {0.f,0.f,0.f,0.f};
  for(int s=0; s<ns; ++s){
    int lo = (s*nch) >> lns, hi = ((s+1)*nch) >> lns;
    if(lo >= hi) continue;                    // never written by pv
    float4 v = p[(size_t)s*N4 + i];
    a.x += v.x; a.y += v.y; a.z += v.z; a.w += v.w;
  }
  reinterpret_cast<float4*>(out)[i] = a;
}

extern "C" void kernel_launch(void* const* d_in, const int* in_sizes, int n_in,
                              void* d_out, int out_size, void* d_ws, size_t ws_size,
                              hipStream_t stream)
{
  (void)in_sizes; (void)n_in; (void)out_size;
  const float* X  = (const float*)d_in[0];
  const float* Wq = (const float*)d_in[1];
  const float* Wk = (const float*)d_in[2];
  const float* Wv = (const float*)d_in[3];
  float* out  = (float*)d_out;
  float* attn = out + (size_t)B_*S_*DK_;            // attention output region (64MB)

  // X bf16 hi/lo images live INSIDE the attn region (dead once scores runs)
  unsigned short* Xth = (unsigned short*)attn;            // 16MB
  unsigned short* Xtl = Xth + (size_t)8388608;            // 16MB

  float* ws = (float*)d_ws;
  float* cmaxf    = ws;                              // [8192]
  float* rcol     = ws + 8192;                       // [8192]
  float* csumpart = ws + 16384;                      // [8192*32]
  float* cmaxpart = ws + 278528;                     // [8192*32]
  unsigned short* Wth = (unsigned short*)(ws + 540672);   // [3][32][5120] shorts
  unsigned short* Wtl = (unsigned short*)(ws + 786432);
  unsigned short* Qh  = (unsigned short*)(ws + 1032192);  // [8192][128] shorts each
  unsigned short* Ql  = (unsigned short*)(ws + 1556480);
  unsigned short* Kh  = (unsigned short*)(ws + 2080768);
  unsigned short* Kl  = (unsigned short*)(ws + 2605056);
  unsigned short* Vth = (unsigned short*)(ws + 3129344);  // [4][128][2048] shorts
  const size_t base = 3653632;                       // floats used so far
  float* part    = ws + base;                        // [ns][4][2048][128]

  int ns = 8, lns = 3;
  if(ws_size < (base + (size_t)8*1048576)*sizeof(float)){ ns = 4; lns = 2; }
  if(ws_size < (base + (size_t)4*1048576)*sizeof(float)){ ns = 2; lns = 1; }
  if(ws_size < (base + (size_t)2*1048576)*sizeof(float)){ ns = 1; lns = 0; }

  conv_kernel<<<dim3(8288), dim3(256), 0, stream>>>(X, Wq, Wk, Wv, Xth, Xtl, Wth, Wtl);
  qkv_mfma_kernel<<<dim3(256,3), dim3(256), 0, stream>>>(Xth, Xtl, Wth, Wtl, Qh, Ql, Kh, Kl, Vth);
  scores_kernel<<<dim3(32,32,4), dim3(256), 0, stream>>>(Qh, Ql, Kh, Kl, attn, cmaxpart, csumpart);
  colreduce_kernel<<<dim3(32), dim3(256), 0, stream>>>(cmaxpart, csumpart, cmaxf, rcol);
  pv_kernel<<<dim3(32,ns,4), dim3(256), 0, stream>>>(attn, cmaxf, rcol, Vth, part, ns);
  pvreduce_kernel<<<dim3(1024), dim3(256), 0, stream>>>(part, out, ns, lns);
}